// Round 18
// baseline (196.385 us; speedup 1.0000x reference)
//
#include <hip/hip_runtime.h>
#include <hip/hip_bf16.h>

#define S_LEN 4096
#define NH    16
#define DD    128
#define HD    2048
#define QB    64
#define KB    64
#define NT    (S_LEN/KB)
#define NS    128          // 32-row subtiles (each 8KB half of a 16KB tile)

typedef __bf16 bf16_t;
typedef bf16_t bf16x8 __attribute__((ext_vector_type(8)));
typedef float  f32x4  __attribute__((ext_vector_type(4)));

static __device__ __forceinline__ bf16x8 pack8(float4 a, float4 b, float s) {
  bf16x8 v;
  v[0]=(bf16_t)(a.x*s); v[1]=(bf16_t)(a.y*s); v[2]=(bf16_t)(a.z*s); v[3]=(bf16_t)(a.w*s);
  v[4]=(bf16_t)(b.x*s); v[5]=(bf16_t)(b.y*s); v[6]=(bf16_t)(b.z*s); v[7]=(bf16_t)(b.w*s);
  return v;
}

static __device__ __forceinline__ void gload_lds16(const void* g, void* l) {
  __builtin_amdgcn_global_load_lds((const __attribute__((address_space(1))) void*)g,
                                   (__attribute__((address_space(3))) void*)l, 16, 0, 0);
}

// ---- prep K: fp32 [s][h][d] -> bf16 frag-major tiles [h][kt][f=(b,c)][lane][8] ----
// rows 0-31 of each 64-tile land in the first 8KB (b=0,1), rows 32-63 in the second.
__global__ __launch_bounds__(256) void prep_k(const float* __restrict__ Kg,
                                              bf16_t* __restrict__ Kp) {
  const int kt = blockIdx.x, h = blockIdx.y, tid = threadIdx.x;
  __shared__ bf16_t tile[KB][DD + 8];
  #pragma unroll
  for (int it = 0; it < 8; ++it) {
    int lin4 = it*256 + tid;
    int r  = lin4 >> 5;
    int dc = (lin4 & 31) * 4;
    float4 a = *(const float4*)(Kg + (size_t)(kt*KB + r)*HD + h*DD + dc);
    tile[r][dc+0]=(bf16_t)a.x; tile[r][dc+1]=(bf16_t)a.y;
    tile[r][dc+2]=(bf16_t)a.z; tile[r][dc+3]=(bf16_t)a.w;
  }
  __syncthreads();
  bf16_t* out = Kp + (size_t)(h*NT + kt)*8192;
  #pragma unroll
  for (int it = 0; it < 4; ++it) {
    int cid = it*256 + tid;
    int f = cid >> 6, l = cid & 63;
    int b = f >> 2, c = f & 3;
    int row = b*16 + (l & 15);
    int d0  = c*32 + (l >> 4)*8;
    bf16x8 v = *(const bf16x8*)(&tile[row][d0]);
    *(bf16x8*)(out + (size_t)cid*8) = v;
  }
}

// ---- prep V: fp32 [s][h][d] -> bf16 frag-major V^T tiles [h][kt][f=(ks,db)][lane][8] ----
// k-slot bijection is closed on [0,32) and [32,64): first 8KB = k rows 0-31.
__global__ __launch_bounds__(256) void prep_v(const float* __restrict__ Vg,
                                              bf16_t* __restrict__ Vp) {
  const int kt = blockIdx.x, h = blockIdx.y, tid = threadIdx.x;
  __shared__ bf16_t tile[KB][DD + 8];
  #pragma unroll
  for (int it = 0; it < 8; ++it) {
    int lin4 = it*256 + tid;
    int r  = lin4 >> 5;
    int dc = (lin4 & 31) * 4;
    float4 a = *(const float4*)(Vg + (size_t)(kt*KB + r)*HD + h*DD + dc);
    tile[r][dc+0]=(bf16_t)a.x; tile[r][dc+1]=(bf16_t)a.y;
    tile[r][dc+2]=(bf16_t)a.z; tile[r][dc+3]=(bf16_t)a.w;
  }
  __syncthreads();
  bf16_t* out = Vp + (size_t)(h*NT + kt)*8192;
  #pragma unroll
  for (int it = 0; it < 4; ++it) {
    int cid = it*256 + tid;
    int f = cid >> 6, l = cid & 63;
    int ks = f >> 3, db = f & 7;
    int d  = db*16 + (l & 15);
    int c0 = ks*32 + (l >> 4)*8;
    bf16x8 v;
    #pragma unroll
    for (int m = 0; m < 8; ++m) {
      int c = c0 + m;
      int k = 32*(c>>5) + 16*((c>>2)&1) + 4*((c>>3)&3) + (c&3);
      v[m] = tile[k][d];
    }
    *(bf16x8*)(out + (size_t)cid*8) = v;
  }
}

// ---- main: QB=64 q-blocks (no merge), KB=32 subtiles, 24KB LDS, 4 blocks/CU ----
__global__ __launch_bounds__(256, 4) void attn_fwd(const float* __restrict__ Qg,
                                                   const bf16_t* __restrict__ Kp,
                                                   const bf16_t* __restrict__ Vp,
                                                   float* __restrict__ Og) {
  // chunked XCD swizzle: 1024 blocks, XCD x owns logical [x*128, x*128+128) = 2 heads
  const int phys = blockIdx.x;
  const int logical = (phys & 7) * 128 + (phys >> 3);
  const int h  = logical >> 6;
  const int qt = logical & 63;       // q-tile of 64 rows
  const int tid  = threadIdx.x;
  const int wid  = tid >> 6;         // 0..3  (one 16-row q-group per wave)
  const int lane = tid & 63;
  const int l16  = lane & 15;
  const int lg   = lane >> 4;
  const int lo16 = lane * 16;

  __shared__ alignas(16) bf16_t Ks[4096];      // 8KB, single-buffered K subtile
  __shared__ alignas(16) bf16_t Vt[2][4096];   // 2x8KB, double-buffered V^T subtile

  // ---- Q fragments (one q-group: 16 rows per wave) ----
  const float qs = 0.08838834764831845f * 1.4426950408889634f;
  bf16x8 qf[4];
  {
    const int qrow = qt*QB + wid*16 + l16;
    const float* qp = Qg + (size_t)qrow*HD + h*DD + lg*8;
    #pragma unroll
    for (int c = 0; c < 4; ++c) {
      float4 a = *(const float4*)(qp + c*32);
      float4 b = *(const float4*)(qp + c*32 + 4);
      qf[c] = pack8(a, b, qs);
    }
  }
  bf16x8 onesf;
  #pragma unroll
  for (int j = 0; j < 8; ++j) onesf[j] = (bf16_t)1.0f;
  asm volatile("" ::: "memory");

  // ---- staging: linear global->LDS DMA (2x16B per thread per operand subtile) ----
  const int lo = tid*16;
  const char* KpH = (const char*)Kp + (size_t)h*1048576;
  const char* VpH = (const char*)Vp + (size_t)h*1048576;
  auto issueK = [&](int s) {
    const char* kg = KpH + (size_t)s*8192;
    char* kl = (char*)&Ks[0];
    gload_lds16(kg + lo,        kl + lo);
    gload_lds16(kg + lo + 4096, kl + lo + 4096);
  };
  auto issueV = [&](int s) {
    const char* vg = VpH + (size_t)s*8192;
    char* vl = (char*)&Vt[s & 1][0];
    gload_lds16(vg + lo,        vl + lo);
    gload_lds16(vg + lo + 4096, vl + lo + 4096);
  };

  f32x4 acc[8];
  f32x4 acc_l;
  #pragma unroll
  for (int i = 0; i < 8; ++i) acc[i] = (f32x4){0.f,0.f,0.f,0.f};
  acc_l = (f32x4){0.f,0.f,0.f,0.f};
  float m_run = -__builtin_inff();

  issueK(0);
  issueV(0);

  for (int s = 0; s < NS; ++s) {
    const int cur = s & 1;
    // ---- K(s),V(s) landed & all prior reads retired -> visible to all ----
    asm volatile("s_waitcnt vmcnt(0) lgkmcnt(0)" ::: "memory");
    __builtin_amdgcn_sched_barrier(0);
    __builtin_amdgcn_s_barrier();

    // V(s+1) -> other buffer; lands any time before top of s+1
    if (s + 1 < NS) issueV(s + 1);

    // ---- S^T = K Q^T : 8 MFMA; reads base + lane*16 + imm ----
    f32x4 sc[2];
    sc[0] = (f32x4){0.f,0.f,0.f,0.f};
    sc[1] = (f32x4){0.f,0.f,0.f,0.f};
    {
      const char* KsB = (const char*)&Ks[0] + lo16;
      __builtin_amdgcn_s_setprio(1);
      #pragma unroll
      for (int b = 0; b < 2; ++b) {
        #pragma unroll
        for (int c = 0; c < 4; ++c) {
          bf16x8 kb = *(const bf16x8*)(KsB + ((b*4 + c) << 10));
          sc[b] = __builtin_amdgcn_mfma_f32_16x16x32_bf16(kb, qf[c], sc[b], 0, 0, 0);
        }
      }
      __builtin_amdgcn_s_setprio(0);
    }
    // lane holds S^T[k = b*16 + lg*4 + r][q = l16] for this 32-row subtile

    // ---- all waves' QK reads retired -> safe to overwrite K buffer ----
    asm volatile("s_waitcnt lgkmcnt(0)" ::: "memory");
    __builtin_amdgcn_sched_barrier(0);
    __builtin_amdgcn_s_barrier();
    if (s + 1 < NS) issueK(s + 1);   // lands under softmax+PV

    // ---- online softmax, lane-local pmax fast path (defer-rescale THR=8) ----
    bf16x8 pp;
    {
      float t0 = fmaxf(fmaxf(sc[0][0], sc[0][1]), sc[0][2]);
      float t1 = fmaxf(fmaxf(sc[0][3], sc[1][0]), sc[1][1]);
      float t2 = fmaxf(sc[1][2], sc[1][3]);
      float pmax = fmaxf(fmaxf(t0, t1), t2);   // LANE-LOCAL max of own 8 scores
      if (!__all(pmax - m_run <= 8.0f)) {
        // rare path: true row max via cross-lane, then rescale
        pmax = fmaxf(pmax, __shfl_xor(pmax, 16));
        pmax = fmaxf(pmax, __shfl_xor(pmax, 32));
        float mnew  = fmaxf(m_run, pmax);
        float alpha = exp2f(m_run - mnew);     // first subtile: exp2(-inf)=0
        m_run = mnew;
        #pragma unroll
        for (int i = 0; i < 8; ++i) {
          #pragma unroll
          for (int r = 0; r < 4; ++r) acc[i][r] *= alpha;
        }
        #pragma unroll
        for (int r = 0; r < 4; ++r) acc_l[r] *= alpha;
      }
      #pragma unroll
      for (int b = 0; b < 2; ++b) {
        #pragma unroll
        for (int r = 0; r < 4; ++r) {
          float pv = exp2f(sc[b][r] - m_run);  // bounded by 2^8
          pp[b*4 + r] = (bf16_t)pv;
        }
      }
    }

    // ---- O^T += V^T P^T ; l += 1^T P^T : 9 MFMA, V read from LDS at use ----
    {
      const char* VtB = (const char*)&Vt[cur][0] + lo16;
      __builtin_amdgcn_s_setprio(1);
      acc_l = __builtin_amdgcn_mfma_f32_16x16x32_bf16(onesf, pp, acc_l, 0, 0, 0);
      #pragma unroll
      for (int db = 0; db < 8; ++db) {
        bf16x8 va = *(const bf16x8*)(VtB + (db << 10));
        acc[db] = __builtin_amdgcn_mfma_f32_16x16x32_bf16(va, pp, acc[db], 0, 0, 0);
      }
      __builtin_amdgcn_s_setprio(0);
    }
  }

  // ---- epilogue: normalize, store O (lane: q=l16, d=db*16+lg*4+r) ----
  {
    const int qrow = qt*QB + wid*16 + l16;
    const float inv = 1.0f / acc_l[0];
    float* op = Og + (size_t)qrow*HD + h*DD + lg*4;
    #pragma unroll
    for (int db = 0; db < 8; ++db) {
      float4 o;
      o.x = acc[db][0]*inv; o.y = acc[db][1]*inv;
      o.z = acc[db][2]*inv; o.w = acc[db][3]*inv;
      *(float4*)(op + db*16) = o;
    }
  }
}

extern "C" void kernel_launch(void* const* d_in, const int* in_sizes, int n_in,
                              void* d_out, int out_size, void* d_ws, size_t ws_size,
                              hipStream_t stream) {
  const float* Q = (const float*)d_in[0];
  const float* K = (const float*)d_in[1];
  const float* V = (const float*)d_in[2];
  float* O = (float*)d_out;
  bf16_t* Kp = (bf16_t*)d_ws;                       // 16.78 MB
  bf16_t* Vp = Kp + (size_t)NH*S_LEN*DD;            // 16.78 MB
  prep_k<<<dim3(NT, NH), 256, 0, stream>>>(K, Kp);
  prep_v<<<dim3(NT, NH), 256, 0, stream>>>(V, Vp);
  attn_fwd<<<dim3(1024), 256, 0, stream>>>(Q, Kp, Vp, O);
}

// Round 19
// 187.541 us; speedup vs baseline: 1.0472x; 1.0472x over previous
//
#include <hip/hip_runtime.h>
#include <hip/hip_bf16.h>

#define S_LEN 4096
#define NH    16
#define DD    128
#define HD    2048
#define QB    128
#define KB    64
#define NT    (S_LEN/KB)
#define NS    128         // 32-row subtiles total
#define SSPL  86          // long blocks: subtiles [0,86); short: [86,128)

typedef __bf16 bf16_t;
typedef bf16_t bf16x8 __attribute__((ext_vector_type(8)));
typedef float  f32x4  __attribute__((ext_vector_type(4)));

static __device__ __forceinline__ bf16x8 pack8(float4 a, float4 b, float s) {
  bf16x8 v;
  v[0]=(bf16_t)(a.x*s); v[1]=(bf16_t)(a.y*s); v[2]=(bf16_t)(a.z*s); v[3]=(bf16_t)(a.w*s);
  v[4]=(bf16_t)(b.x*s); v[5]=(bf16_t)(b.y*s); v[6]=(bf16_t)(b.z*s); v[7]=(bf16_t)(b.w*s);
  return v;
}

static __device__ __forceinline__ void gload_lds16(const void* g, void* l) {
  __builtin_amdgcn_global_load_lds((const __attribute__((address_space(1))) void*)g,
                                   (__attribute__((address_space(3))) void*)l, 16, 0, 0);
}

// ---- fused prep: z=0 -> K frag-major tiles; z=1 -> V^T frag-major tiles ----
// K: [h][kt][f=(b,c)][lane][8]; rows 0-31 in first 8KB, 32-63 in second.
// V: [h][kt][f=(ks,db)][lane][8]; k-slot bijection closed on [0,32)/[32,64).
__global__ __launch_bounds__(256) void prep_kv(const float* __restrict__ Kg,
                                               const float* __restrict__ Vg,
                                               bf16_t* __restrict__ Kp,
                                               bf16_t* __restrict__ Vp) {
  const int kt = blockIdx.x, h = blockIdx.y, which = blockIdx.z, tid = threadIdx.x;
  const float* src = which ? Vg : Kg;
  __shared__ bf16_t tile[KB][DD + 8];
  #pragma unroll
  for (int it = 0; it < 8; ++it) {
    int lin4 = it*256 + tid;
    int r  = lin4 >> 5;
    int dc = (lin4 & 31) * 4;
    float4 a = *(const float4*)(src + (size_t)(kt*KB + r)*HD + h*DD + dc);
    tile[r][dc+0]=(bf16_t)a.x; tile[r][dc+1]=(bf16_t)a.y;
    tile[r][dc+2]=(bf16_t)a.z; tile[r][dc+3]=(bf16_t)a.w;
  }
  __syncthreads();
  if (which == 0) {
    bf16_t* out = Kp + (size_t)(h*NT + kt)*8192;
    #pragma unroll
    for (int it = 0; it < 4; ++it) {
      int cid = it*256 + tid;
      int f = cid >> 6, l = cid & 63;
      int b = f >> 2, c = f & 3;
      int row = b*16 + (l & 15);
      int d0  = c*32 + (l >> 4)*8;
      bf16x8 v = *(const bf16x8*)(&tile[row][d0]);
      *(bf16x8*)(out + (size_t)cid*8) = v;
    }
  } else {
    bf16_t* out = Vp + (size_t)(h*NT + kt)*8192;
    #pragma unroll
    for (int it = 0; it < 4; ++it) {
      int cid = it*256 + tid;
      int f = cid >> 6, l = cid & 63;
      int ks = f >> 3, db = f & 7;
      int d  = db*16 + (l & 15);
      int c0 = ks*32 + (l >> 4)*8;
      bf16x8 v;
      #pragma unroll
      for (int m = 0; m < 8; ++m) {
        int c = c0 + m;
        int k = 32*(c>>5) + 16*((c>>2)&1) + 4*((c>>3)&3) + (c&3);
        v[m] = tile[k][d];
      }
      *(bf16x8*)(out + (size_t)cid*8) = v;
    }
  }
}

// ---- main: 4-wave blocks, 32-row subtiles, K+V dbuf (32KB), 1 barrier/subtile,
// ---- uneven KV-split (86/42 subtiles) longs-first, 3 blocks/CU resident ----
__global__ __launch_bounds__(256, 3) void attn_fwd(const float* __restrict__ Qg,
                                                   const bf16_t* __restrict__ Kp,
                                                   const bf16_t* __restrict__ Vp,
                                                   float* __restrict__ A0,   // = d_out, raw partial 0
                                                   float* __restrict__ A1,
                                                   float* __restrict__ lmW) {
  // chunked XCD swizzle: 1024 blocks, XCD x owns logical [x*128, x*128+128) = 2 heads.
  // Within each head's 64 logicals: first 32 = LONG (subtiles [0,86)), next 32 = SHORT.
  const int phys = blockIdx.x;
  const int logical = (phys & 7) * 128 + (phys >> 3);
  const int h   = logical >> 6;
  const int rem = logical & 63;
  const int p   = rem >> 5;          // 0 = long, 1 = short
  const int qt  = rem & 31;          // q-tile of 128 rows
  const int tid  = threadIdx.x;
  const int wid  = tid >> 6;         // 0..3
  const int lane = tid & 63;
  const int l16  = lane & 15;
  const int lg   = lane >> 4;
  const int lo16 = lane * 16;
  const int s0   = p ? SSPL : 0;
  const int sEnd = p ? NS : SSPL;

  __shared__ alignas(16) bf16_t Ks[2][4096];   // 2x8KB, K subtile dbuf
  __shared__ alignas(16) bf16_t Vt[2][4096];   // 2x8KB, V^T subtile dbuf

  // ---- Q fragments for 2 q-groups (B-operand of swapped QK^T) ----
  const float qs = 0.08838834764831845f * 1.4426950408889634f;
  bf16x8 qf[2][4];
  #pragma unroll
  for (int g = 0; g < 2; ++g) {
    const int qrow = qt*QB + wid*32 + g*16 + l16;
    const float* qp = Qg + (size_t)qrow*HD + h*DD + lg*8;
    #pragma unroll
    for (int c = 0; c < 4; ++c) {
      float4 a = *(const float4*)(qp + c*32);
      float4 b = *(const float4*)(qp + c*32 + 4);
      qf[g][c] = pack8(a, b, qs);
    }
  }
  bf16x8 onesf;
  #pragma unroll
  for (int j = 0; j < 8; ++j) onesf[j] = (bf16_t)1.0f;
  asm volatile("" ::: "memory");

  // ---- staging: linear global->LDS DMA (2+2 x16B per thread per subtile) ----
  const int lo = tid*16;
  const char* KpH = (const char*)Kp + (size_t)h*1048576;
  const char* VpH = (const char*)Vp + (size_t)h*1048576;
  auto issue = [&](int s) {
    int b = s & 1;
    const char* kg = KpH + (size_t)s*8192;
    const char* vg = VpH + (size_t)s*8192;
    char* kl = (char*)&Ks[b][0];
    char* vl = (char*)&Vt[b][0];
    gload_lds16(kg + lo,        kl + lo);
    gload_lds16(kg + lo + 4096, kl + lo + 4096);
    gload_lds16(vg + lo,        vl + lo);
    gload_lds16(vg + lo + 4096, vl + lo + 4096);
  };

  f32x4 acc[2][8];
  f32x4 acc_l[2];
  #pragma unroll
  for (int g = 0; g < 2; ++g) {
    #pragma unroll
    for (int i = 0; i < 8; ++i) acc[g][i] = (f32x4){0.f,0.f,0.f,0.f};
    acc_l[g] = (f32x4){0.f,0.f,0.f,0.f};
  }
  float m_run[2] = {-__builtin_inff(), -__builtin_inff()};

  // prologue: s0, s0+1 in flight; wait s0 landed (4 of s0+1 remain)
  issue(s0);
  issue(s0 + 1);
  asm volatile("s_waitcnt vmcnt(4)" ::: "memory");
  __builtin_amdgcn_s_barrier();
  __builtin_amdgcn_sched_barrier(0);

  for (int s = s0; s < sEnd; ++s) {
    const int cur = s & 1;
    const char* KsB = (const char*)&Ks[cur][0] + lo16;
    const char* VtB = (const char*)&Vt[cur][0] + lo16;

    // ---- S^T = K Q^T : 16 MFMA; reads base + lane*16 + imm ----
    f32x4 sc[2][2];
    #pragma unroll
    for (int g = 0; g < 2; ++g) {
      sc[g][0] = (f32x4){0.f,0.f,0.f,0.f};
      sc[g][1] = (f32x4){0.f,0.f,0.f,0.f};
    }
    __builtin_amdgcn_s_setprio(1);
    #pragma unroll
    for (int b = 0; b < 2; ++b) {
      #pragma unroll
      for (int c = 0; c < 4; ++c) {
        bf16x8 kb = *(const bf16x8*)(KsB + ((b*4 + c) << 10));
        sc[0][b] = __builtin_amdgcn_mfma_f32_16x16x32_bf16(kb, qf[0][c], sc[0][b], 0, 0, 0);
        sc[1][b] = __builtin_amdgcn_mfma_f32_16x16x32_bf16(kb, qf[1][c], sc[1][b], 0, 0, 0);
      }
    }
    __builtin_amdgcn_s_setprio(0);
    // lane holds S^T[k = b*16 + lg*4 + r][q = g-group row l16]

    // ---- online softmax, lane-local pmax fast path (defer-rescale THR=8) ----
    bf16x8 pp[2];
    #pragma unroll
    for (int g = 0; g < 2; ++g) {
      float pmax;
      {
        float t0 = fmaxf(fmaxf(sc[g][0][0], sc[g][0][1]), sc[g][0][2]);
        float t1 = fmaxf(fmaxf(sc[g][0][3], sc[g][1][0]), sc[g][1][1]);
        float t2 = fmaxf(sc[g][1][2], sc[g][1][3]);
        pmax = fmaxf(fmaxf(t0, t1), t2);   // LANE-LOCAL max of own 8 scores
      }
      if (!__all(pmax - m_run[g] <= 8.0f)) {
        // rare path: true row max via cross-lane, then rescale
        pmax = fmaxf(pmax, __shfl_xor(pmax, 16));
        pmax = fmaxf(pmax, __shfl_xor(pmax, 32));
        float mnew  = fmaxf(m_run[g], pmax);
        float alpha = exp2f(m_run[g] - mnew);    // first subtile: exp2(-inf)=0
        m_run[g] = mnew;
        #pragma unroll
        for (int i = 0; i < 8; ++i) {
          #pragma unroll
          for (int r = 0; r < 4; ++r) acc[g][i][r] *= alpha;
        }
        #pragma unroll
        for (int r = 0; r < 4; ++r) acc_l[g][r] *= alpha;
      }
      #pragma unroll
      for (int b = 0; b < 2; ++b) {
        #pragma unroll
        for (int r = 0; r < 4; ++r) {
          float pv = exp2f(sc[g][b][r] - m_run[g]);   // bounded by 2^8
          pp[g][b*4 + r] = (bf16_t)pv;
        }
      }
    }

    // ---- O^T += V^T P^T ; l += 1^T P^T : 18 MFMA, V frags feed both groups ----
    __builtin_amdgcn_s_setprio(1);
    acc_l[0] = __builtin_amdgcn_mfma_f32_16x16x32_bf16(onesf, pp[0], acc_l[0], 0, 0, 0);
    acc_l[1] = __builtin_amdgcn_mfma_f32_16x16x32_bf16(onesf, pp[1], acc_l[1], 0, 0, 0);
    #pragma unroll
    for (int db = 0; db < 8; ++db) {
      bf16x8 va = *(const bf16x8*)(VtB + (db << 10));
      acc[0][db] = __builtin_amdgcn_mfma_f32_16x16x32_bf16(va, pp[0], acc[0][db], 0, 0, 0);
      acc[1][db] = __builtin_amdgcn_mfma_f32_16x16x32_bf16(va, pp[1], acc[1][db], 0, 0, 0);
    }
    __builtin_amdgcn_s_setprio(0);

    // ---- ONE sync point: my LDS reads retired + my s+1 loads landed ----
    asm volatile("s_waitcnt vmcnt(0) lgkmcnt(0)" ::: "memory");
    __builtin_amdgcn_sched_barrier(0);
    __builtin_amdgcn_s_barrier();
    // buf[cur] free for everyone; s+1 fully visible -> refill cur with s+2
    if (s + 2 < sEnd) issue(s + 2);
  }

  // ---- epilogue: store RAW partial acc + (l, m) per q-row ----
  float* Ap = p ? A1 : A0;
  #pragma unroll
  for (int g = 0; g < 2; ++g) {
    const int qrow = qt*QB + wid*32 + g*16 + l16;
    float* op = Ap + (size_t)qrow*HD + h*DD + lg*4;
    #pragma unroll
    for (int db = 0; db < 8; ++db) {
      float4 o;
      o.x = acc[g][db][0]; o.y = acc[g][db][1];
      o.z = acc[g][db][2]; o.w = acc[g][db][3];
      *(float4*)(op + db*16) = o;
    }
    if (lg == 0) {
      size_t row = (size_t)h*S_LEN + qrow;
      lmW[(size_t)p*131072 + row]         = acc_l[g][0];  // l
      lmW[(size_t)p*131072 + 65536 + row] = m_run[g];     // m (exp2 domain)
    }
  }
}

// ---- merge: O = (A0*2^(m0-m) + A1*2^(m1-m)) / (l0*2^(m0-m) + l1*2^(m1-m)) ----
__global__ __launch_bounds__(256) void merge2(const float* __restrict__ A1,
                                              const float* __restrict__ lmW,
                                              float* __restrict__ O) {
  size_t idx = (size_t)blockIdx.x*256 + threadIdx.x;   // one float4 of O
  size_t sh = idx >> 5;          // s*16 + h
  int hh = (int)(sh & 15);
  int ss = (int)(sh >> 4);
  size_t row = (size_t)hh*S_LEN + ss;
  float l0 = lmW[row],          m0 = lmW[65536 + row];
  float l1 = lmW[131072 + row], m1 = lmW[196608 + row];
  float m  = fmaxf(m0, m1);
  float w0 = exp2f(m0 - m), w1 = exp2f(m1 - m);
  float inv = 1.0f / (l0*w0 + l1*w1);
  float4 a0 = *(const float4*)(O  + idx*4);
  float4 a1 = *(const float4*)(A1 + idx*4);
  float4 o;
  o.x = (a0.x*w0 + a1.x*w1)*inv;
  o.y = (a0.y*w0 + a1.y*w1)*inv;
  o.z = (a0.z*w0 + a1.z*w1)*inv;
  o.w = (a0.w*w0 + a1.w*w1)*inv;
  *(float4*)(O + idx*4) = o;
}

extern "C" void kernel_launch(void* const* d_in, const int* in_sizes, int n_in,
                              void* d_out, int out_size, void* d_ws, size_t ws_size,
                              hipStream_t stream) {
  const float* Q = (const float*)d_in[0];
  const float* K = (const float*)d_in[1];
  const float* V = (const float*)d_in[2];
  float* O = (float*)d_out;
  bf16_t* Kp = (bf16_t*)d_ws;                   // 16.78 MB
  bf16_t* Vp = Kp + (size_t)8388608;            // 16.78 MB
  float*  A1 = (float*)(Vp + (size_t)8388608);  // 33.55 MB raw partial 1
  float*  lm = A1 + (size_t)8388608;            // 1.05 MB (4 planes of 65536)
  prep_kv<<<dim3(NT, NH, 2), 256, 0, stream>>>(K, V, Kp, Vp);
  attn_fwd<<<dim3(1024), 256, 0, stream>>>(Q, Kp, Vp, O, A1, lm);
  merge2<<<dim3(8192), 256, 0, stream>>>(A1, lm, O);
}

// Round 20
// 177.369 us; speedup vs baseline: 1.1072x; 1.0573x over previous
//
#include <hip/hip_runtime.h>
#include <hip/hip_bf16.h>

#define S_LEN 4096
#define NH    16
#define DD    128
#define HD    2048
#define QB    128
#define KB    64
#define NT    (S_LEN/KB)

typedef __bf16 bf16_t;
typedef bf16_t bf16x8 __attribute__((ext_vector_type(8)));
typedef float  f32x4  __attribute__((ext_vector_type(4)));

static __device__ __forceinline__ bf16x8 pack8(float4 a, float4 b, float s) {
  bf16x8 v;
  v[0]=(bf16_t)(a.x*s); v[1]=(bf16_t)(a.y*s); v[2]=(bf16_t)(a.z*s); v[3]=(bf16_t)(a.w*s);
  v[4]=(bf16_t)(b.x*s); v[5]=(bf16_t)(b.y*s); v[6]=(bf16_t)(b.z*s); v[7]=(bf16_t)(b.w*s);
  return v;
}

static __device__ __forceinline__ void gload_lds16(const void* g, void* l) {
  __builtin_amdgcn_global_load_lds((const __attribute__((address_space(1))) void*)g,
                                   (__attribute__((address_space(3))) void*)l, 16, 0, 0);
}

// ---- fused prep: z=0 -> K frag-major tiles; z=1 -> V^T frag-major tiles ----
// K: [h][kt][f=(b,c)][lane][8], lane l of frag (b,c) holds K[kt*64+b*16+(l&15)][c*32+(l>>4)*8..+8]
// V: [h][kt][f=(ks,db)][lane][8] with MFMA k-slot bijection baked in.
__global__ __launch_bounds__(256) void prep_kv(const float* __restrict__ Kg,
                                               const float* __restrict__ Vg,
                                               bf16_t* __restrict__ Kp,
                                               bf16_t* __restrict__ Vp) {
  const int kt = blockIdx.x, h = blockIdx.y, which = blockIdx.z, tid = threadIdx.x;
  const float* src = which ? Vg : Kg;
  __shared__ bf16_t tile[KB][DD + 8];
  #pragma unroll
  for (int it = 0; it < 8; ++it) {
    int lin4 = it*256 + tid;
    int r  = lin4 >> 5;
    int dc = (lin4 & 31) * 4;
    float4 a = *(const float4*)(src + (size_t)(kt*KB + r)*HD + h*DD + dc);
    tile[r][dc+0]=(bf16_t)a.x; tile[r][dc+1]=(bf16_t)a.y;
    tile[r][dc+2]=(bf16_t)a.z; tile[r][dc+3]=(bf16_t)a.w;
  }
  __syncthreads();
  if (which == 0) {
    bf16_t* out = Kp + (size_t)(h*NT + kt)*8192;
    #pragma unroll
    for (int it = 0; it < 4; ++it) {
      int cid = it*256 + tid;
      int f = cid >> 6, l = cid & 63;
      int b = f >> 2, c = f & 3;
      int row = b*16 + (l & 15);
      int d0  = c*32 + (l >> 4)*8;
      bf16x8 v = *(const bf16x8*)(&tile[row][d0]);
      *(bf16x8*)(out + (size_t)cid*8) = v;
    }
  } else {
    bf16_t* out = Vp + (size_t)(h*NT + kt)*8192;
    #pragma unroll
    for (int it = 0; it < 4; ++it) {
      int cid = it*256 + tid;
      int f = cid >> 6, l = cid & 63;
      int ks = f >> 3, db = f & 7;
      int d  = db*16 + (l & 15);
      int c0 = ks*32 + (l >> 4)*8;
      bf16x8 v;
      #pragma unroll
      for (int m = 0; m < 8; ++m) {
        int c = c0 + m;
        int k = 32*(c>>5) + 16*((c>>2)&1) + 4*((c>>3)&3) + (c&3);
        v[m] = tile[k][d];
      }
      *(bf16x8*)(out + (size_t)cid*8) = v;
    }
  }
}

// QK cluster: DST[2][4] += K-frags x qf; reads are base + lane*16 + imm
#define QK_COMPUTE(DST, KSBASE)                                                  \
  do {                                                                           \
    _Pragma("unroll")                                                            \
    for (int b_ = 0; b_ < 4; ++b_) {                                             \
      _Pragma("unroll")                                                          \
      for (int c_ = 0; c_ < 4; ++c_) {                                           \
        bf16x8 kb_ = *(const bf16x8*)((KSBASE) + ((b_*4 + c_) << 10));           \
        DST[0][b_] = __builtin_amdgcn_mfma_f32_16x16x32_bf16(kb_, qf[0][c_], DST[0][b_], 0, 0, 0); \
        DST[1][b_] = __builtin_amdgcn_mfma_f32_16x16x32_bf16(kb_, qf[1][c_], DST[1][b_], 0, 0, 0); \
      }                                                                          \
    }                                                                            \
  } while (0)

// softmax(SC) -> pp ; then PV from vf regs.
// LOCAL-pmax fast path: no cross-lane shuffles unless rescale needed.
#define SOFTMAX_PV(SC)                                                           \
  do {                                                                           \
    bf16x8 pp[2][2];                                                             \
    _Pragma("unroll")                                                            \
    for (int g = 0; g < 2; ++g) {                                                \
      float pmax;                                                                \
      {                                                                          \
        float a0 = fmaxf(fmaxf(SC[g][0][0], SC[g][0][1]), SC[g][0][2]);          \
        float a1 = fmaxf(fmaxf(SC[g][0][3], SC[g][1][0]), SC[g][1][1]);          \
        float a2 = fmaxf(fmaxf(SC[g][1][2], SC[g][1][3]), SC[g][2][0]);          \
        float a3 = fmaxf(fmaxf(SC[g][2][1], SC[g][2][2]), SC[g][2][3]);          \
        float a4 = fmaxf(fmaxf(SC[g][3][0], SC[g][3][1]), SC[g][3][2]);          \
        float b0 = fmaxf(fmaxf(a0, a1), a2);                                     \
        float b1 = fmaxf(fmaxf(a3, a4), SC[g][3][3]);                            \
        pmax = fmaxf(b0, b1);   /* LANE-LOCAL max (16 own scores) */             \
      }                                                                          \
      if (!__all(pmax - m_run[g] <= 8.0f)) {                                     \
        /* rare path: true row max via cross-lane, then rescale */               \
        pmax = fmaxf(pmax, __shfl_xor(pmax, 16));                                \
        pmax = fmaxf(pmax, __shfl_xor(pmax, 32));                                \
        float mnew  = fmaxf(m_run[g], pmax);                                     \
        float alpha = exp2f(m_run[g] - mnew);                                    \
        m_run[g] = mnew;                                                         \
        _Pragma("unroll")                                                        \
        for (int i = 0; i < 8; ++i) {                                            \
          _Pragma("unroll")                                                      \
          for (int r = 0; r < 4; ++r) acc[g][i][r] *= alpha;                     \
        }                                                                        \
        _Pragma("unroll")                                                        \
        for (int r = 0; r < 4; ++r) acc_l[g][r] *= alpha;                        \
      }                                                                          \
      _Pragma("unroll")                                                          \
      for (int b_ = 0; b_ < 4; ++b_) {                                           \
        _Pragma("unroll")                                                        \
        for (int r = 0; r < 4; ++r) {                                            \
          float p = exp2f(SC[g][b_][r] - m_run[g]);   /* bounded by 2^8 */       \
          pp[g][b_ >> 1][(b_ & 1)*4 + r] = (bf16_t)p;                            \
        }                                                                        \
      }                                                                          \
    }                                                                            \
    __builtin_amdgcn_s_setprio(1);                                               \
    _Pragma("unroll")                                                            \
    for (int ks = 0; ks < 2; ++ks) {                                             \
      acc_l[0] = __builtin_amdgcn_mfma_f32_16x16x32_bf16(onesf, pp[0][ks], acc_l[0], 0, 0, 0); \
      acc_l[1] = __builtin_amdgcn_mfma_f32_16x16x32_bf16(onesf, pp[1][ks], acc_l[1], 0, 0, 0); \
      _Pragma("unroll")                                                          \
      for (int db = 0; db < 8; ++db) {                                           \
        bf16x8 va = vf[ks*8 + db];                                               \
        acc[0][db] = __builtin_amdgcn_mfma_f32_16x16x32_bf16(va, pp[0][ks], acc[0][db], 0, 0, 0); \
        acc[1][db] = __builtin_amdgcn_mfma_f32_16x16x32_bf16(va, pp[1][ks], acc[1][db], 0, 0, 0); \
      }                                                                          \
    }                                                                            \
    __builtin_amdgcn_s_setprio(0);                                               \
  } while (0)

__global__ __launch_bounds__(256, 2) void attn_fwd(const float* __restrict__ Qg,
                                                   const bf16_t* __restrict__ Kp,
                                                   const bf16_t* __restrict__ Vp,
                                                   float* __restrict__ Og) {
  // chunked XCD swizzle: 512 blocks, XCD x owns logical [x*64, x*64+64) = 2 heads
  const int phys = blockIdx.x;
  const int logical = (phys & 7) * 64 + (phys >> 3);
  const int h  = logical >> 5;
  const int qt = logical & 31;       // q-tile of 128 rows
  const int tid  = threadIdx.x;
  const int wid  = tid >> 6;         // 0..3
  const int lane = tid & 63;
  const int l16  = lane & 15;
  const int lg   = lane >> 4;
  const int lo16 = lane * 16;

  __shared__ alignas(16) bf16_t Ks[2][8192];   // 16KB each, frag-major
  __shared__ alignas(16) bf16_t Vt[2][8192];   // 16KB each, frag-major

  // ---- Q fragments for 2 q-groups (B-operand of swapped QK^T) ----
  const float qs = 0.08838834764831845f * 1.4426950408889634f;
  bf16x8 qf[2][4];
  #pragma unroll
  for (int g = 0; g < 2; ++g) {
    const int qrow = qt*QB + wid*32 + g*16 + l16;
    const float* qp = Qg + (size_t)qrow*HD + h*DD + lg*8;
    #pragma unroll
    for (int c = 0; c < 4; ++c) {
      float4 a = *(const float4*)(qp + c*32);
      float4 b = *(const float4*)(qp + c*32 + 4);
      qf[g][c] = pack8(a, b, qs);
    }
  }
  bf16x8 onesf;
  #pragma unroll
  for (int j = 0; j < 8; ++j) onesf[j] = (bf16_t)1.0f;
  asm volatile("" ::: "memory");

  // ---- staging: pure linear global->LDS DMA (8x16B per thread per tile) ----
  const int lo = tid*16;
  auto issue = [&](int kt) {
    int b = kt & 1;
    const char* kg = (const char*)(Kp + (size_t)(h*NT + kt)*8192);
    const char* vg = (const char*)(Vp + (size_t)(h*NT + kt)*8192);
    char* kl = (char*)&Ks[b][0];
    char* vl = (char*)&Vt[b][0];
    #pragma unroll
    for (int p = 0; p < 4; ++p) gload_lds16(kg + lo + p*4096, kl + lo + p*4096);
    #pragma unroll
    for (int p = 0; p < 4; ++p) gload_lds16(vg + lo + p*4096, vl + lo + p*4096);
  };

  f32x4 acc[2][8];
  f32x4 acc_l[2];
  #pragma unroll
  for (int g = 0; g < 2; ++g) {
    #pragma unroll
    for (int i = 0; i < 8; ++i) acc[g][i] = (f32x4){0.f,0.f,0.f,0.f};
    acc_l[g] = (f32x4){0.f,0.f,0.f,0.f};
  }
  float m_run[2] = {-__builtin_inff(), -__builtin_inff()};

  issue(0);
  issue(1);
  asm volatile("s_waitcnt vmcnt(8)" ::: "memory");  // tile 0 arrived (8 of tile1 in flight)
  __builtin_amdgcn_s_barrier();
  __builtin_amdgcn_sched_barrier(0);

  // prologue QK(0)
  f32x4 sc[2][4];
  #pragma unroll
  for (int g = 0; g < 2; ++g)
    #pragma unroll
    for (int b = 0; b < 4; ++b) sc[g][b] = (f32x4){0.f,0.f,0.f,0.f};
  {
    const char* KsB = (const char*)&Ks[0][0] + lo16;
    QK_COMPUTE(sc, KsB);
  }

  for (int kt = 0; kt < NT-1; ++kt) {
    const int cur = kt & 1;
    // ---- V hoist (tile kt) from buf[cur] ----
    bf16x8 vf[16];
    {
      const char* VtB = (const char*)&Vt[cur][0] + lo16;
      #pragma unroll
      for (int f = 0; f < 16; ++f) vf[f] = *(const bf16x8*)(VtB + (f << 10));
    }
    asm volatile("s_waitcnt lgkmcnt(0)" ::: "memory");
    __builtin_amdgcn_sched_barrier(0);
    __builtin_amdgcn_s_barrier();            // #1: all reads of buf[cur] complete
    if (kt + 2 < NT) {
      issue(kt + 2);                         // DMA into buf[cur]
      asm volatile("s_waitcnt vmcnt(8)" ::: "memory");   // tile kt+1 fully arrived
    } else {
      asm volatile("s_waitcnt vmcnt(0)" ::: "memory");
    }
    __builtin_amdgcn_s_barrier();            // #2: tile kt+1 visible to all waves
    __builtin_amdgcn_sched_barrier(0);

    // ---- QK(kt+1) -> sc_next  ||  softmax(kt) + PV(kt)  (independent DAGs) ----
    f32x4 scn[2][4];
    #pragma unroll
    for (int g = 0; g < 2; ++g)
      #pragma unroll
      for (int b = 0; b < 4; ++b) scn[g][b] = (f32x4){0.f,0.f,0.f,0.f};
    {
      const char* KsB = (const char*)&Ks[cur ^ 1][0] + lo16;
      QK_COMPUTE(scn, KsB);
    }
    SOFTMAX_PV(sc);

    #pragma unroll
    for (int g = 0; g < 2; ++g)
      #pragma unroll
      for (int b = 0; b < 4; ++b) sc[g][b] = scn[g][b];
  }

  // ---- tail tile NT-1: V hoist + softmax + PV (no more DMA) ----
  {
    bf16x8 vf[16];
    const char* VtB = (const char*)&Vt[(NT-1) & 1][0] + lo16;
    #pragma unroll
    for (int f = 0; f < 16; ++f) vf[f] = *(const bf16x8*)(VtB + (f << 10));
    SOFTMAX_PV(sc);
  }

  // ---- epilogue: normalize, store O (lane: q=g*16+l16, d=db*16+lg*4+r) ----
  #pragma unroll
  for (int g = 0; g < 2; ++g) {
    const int qrow = qt*QB + wid*32 + g*16 + l16;
    const float inv = 1.0f / acc_l[g][0];
    float* op = Og + (size_t)qrow*HD + h*DD + lg*4;
    #pragma unroll
    for (int db = 0; db < 8; ++db) {
      float4 o;
      o.x = acc[g][db][0]*inv; o.y = acc[g][db][1]*inv;
      o.z = acc[g][db][2]*inv; o.w = acc[g][db][3]*inv;
      *(float4*)(op + db*16) = o;
    }
  }
}

extern "C" void kernel_launch(void* const* d_in, const int* in_sizes, int n_in,
                              void* d_out, int out_size, void* d_ws, size_t ws_size,
                              hipStream_t stream) {
  const float* Q = (const float*)d_in[0];
  const float* K = (const float*)d_in[1];
  const float* V = (const float*)d_in[2];
  float* O = (float*)d_out;
  bf16_t* Kp = (bf16_t*)d_ws;                       // 16.78 MB
  bf16_t* Vp = Kp + (size_t)NH*S_LEN*DD;            // 16.78 MB
  prep_kv<<<dim3(NT, NH, 2), 256, 0, stream>>>(K, V, Kp, Vp);
  attn_fwd<<<dim3(512), 256, 0, stream>>>(Q, Kp, Vp, O);
}

// Round 21
// 176.511 us; speedup vs baseline: 1.1126x; 1.0049x over previous
//
#include <hip/hip_runtime.h>
#include <hip/hip_bf16.h>

#define S_LEN 4096
#define NH    16
#define DD    128
#define HD    2048
#define QB    128
#define KB    64
#define NT    (S_LEN/KB)

typedef __bf16 bf16_t;
typedef bf16_t bf16x8 __attribute__((ext_vector_type(8)));
typedef float  f32x4  __attribute__((ext_vector_type(4)));

static __device__ __forceinline__ bf16x8 pack8(float4 a, float4 b, float s) {
  bf16x8 v;
  v[0]=(bf16_t)(a.x*s); v[1]=(bf16_t)(a.y*s); v[2]=(bf16_t)(a.z*s); v[3]=(bf16_t)(a.w*s);
  v[4]=(bf16_t)(b.x*s); v[5]=(bf16_t)(b.y*s); v[6]=(bf16_t)(b.z*s); v[7]=(bf16_t)(b.w*s);
  return v;
}

static __device__ __forceinline__ void gload_lds16(const void* g, void* l) {
  __builtin_amdgcn_global_load_lds((const __attribute__((address_space(1))) void*)g,
                                   (__attribute__((address_space(3))) void*)l, 16, 0, 0);
}

// ---- fused prep: z=0 -> K frag-major tiles; z=1 -> V^T frag-major tiles ----
__global__ __launch_bounds__(256) void prep_kv(const float* __restrict__ Kg,
                                               const float* __restrict__ Vg,
                                               bf16_t* __restrict__ Kp,
                                               bf16_t* __restrict__ Vp) {
  const int kt = blockIdx.x, h = blockIdx.y, which = blockIdx.z, tid = threadIdx.x;
  const float* src = which ? Vg : Kg;
  __shared__ bf16_t tile[KB][DD + 8];
  #pragma unroll
  for (int it = 0; it < 8; ++it) {
    int lin4 = it*256 + tid;
    int r  = lin4 >> 5;
    int dc = (lin4 & 31) * 4;
    float4 a = *(const float4*)(src + (size_t)(kt*KB + r)*HD + h*DD + dc);
    tile[r][dc+0]=(bf16_t)a.x; tile[r][dc+1]=(bf16_t)a.y;
    tile[r][dc+2]=(bf16_t)a.z; tile[r][dc+3]=(bf16_t)a.w;
  }
  __syncthreads();
  if (which == 0) {
    bf16_t* out = Kp + (size_t)(h*NT + kt)*8192;
    #pragma unroll
    for (int it = 0; it < 4; ++it) {
      int cid = it*256 + tid;
      int f = cid >> 6, l = cid & 63;
      int b = f >> 2, c = f & 3;
      int row = b*16 + (l & 15);
      int d0  = c*32 + (l >> 4)*8;
      bf16x8 v = *(const bf16x8*)(&tile[row][d0]);
      *(bf16x8*)(out + (size_t)cid*8) = v;
    }
  } else {
    bf16_t* out = Vp + (size_t)(h*NT + kt)*8192;
    #pragma unroll
    for (int it = 0; it < 4; ++it) {
      int cid = it*256 + tid;
      int f = cid >> 6, l = cid & 63;
      int ks = f >> 3, db = f & 7;
      int d  = db*16 + (l & 15);
      int c0 = ks*32 + (l >> 4)*8;
      bf16x8 v;
      #pragma unroll
      for (int m = 0; m < 8; ++m) {
        int c = c0 + m;
        int k = 32*(c>>5) + 16*((c>>2)&1) + 4*((c>>3)&3) + (c&3);
        v[m] = tile[k][d];
      }
      *(bf16x8*)(out + (size_t)cid*8) = v;
    }
  }
}

// QK cluster: DST[2][4] += K-frags x qf; reads are base + lane*16 + imm
#define QK_COMPUTE(DST, KSBASE)                                                  \
  do {                                                                           \
    _Pragma("unroll")                                                            \
    for (int b_ = 0; b_ < 4; ++b_) {                                             \
      _Pragma("unroll")                                                          \
      for (int c_ = 0; c_ < 4; ++c_) {                                           \
        bf16x8 kb_ = *(const bf16x8*)((KSBASE) + ((b_*4 + c_) << 10));           \
        DST[0][b_] = __builtin_amdgcn_mfma_f32_16x16x32_bf16(kb_, qf[0][c_], DST[0][b_], 0, 0, 0); \
        DST[1][b_] = __builtin_amdgcn_mfma_f32_16x16x32_bf16(kb_, qf[1][c_], DST[1][b_], 0, 0, 0); \
      }                                                                          \
    }                                                                            \
  } while (0)

// softmax(SC) -> pp ; then PV from vf regs.
// LOCAL-pmax fast path: no cross-lane shuffles unless rescale needed.
#define SOFTMAX_PV(SC)                                                           \
  do {                                                                           \
    bf16x8 pp[2][2];                                                             \
    _Pragma("unroll")                                                            \
    for (int g = 0; g < 2; ++g) {                                                \
      float pmax;                                                                \
      {                                                                          \
        float a0 = fmaxf(fmaxf(SC[g][0][0], SC[g][0][1]), SC[g][0][2]);          \
        float a1 = fmaxf(fmaxf(SC[g][0][3], SC[g][1][0]), SC[g][1][1]);          \
        float a2 = fmaxf(fmaxf(SC[g][1][2], SC[g][1][3]), SC[g][2][0]);          \
        float a3 = fmaxf(fmaxf(SC[g][2][1], SC[g][2][2]), SC[g][2][3]);          \
        float a4 = fmaxf(fmaxf(SC[g][3][0], SC[g][3][1]), SC[g][3][2]);          \
        float b0 = fmaxf(fmaxf(a0, a1), a2);                                     \
        float b1 = fmaxf(fmaxf(a3, a4), SC[g][3][3]);                            \
        pmax = fmaxf(b0, b1);   /* LANE-LOCAL max (16 own scores) */             \
      }                                                                          \
      if (!__all(pmax - m_run[g] <= 8.0f)) {                                     \
        /* rare path: true row max via cross-lane, then rescale */               \
        pmax = fmaxf(pmax, __shfl_xor(pmax, 16));                                \
        pmax = fmaxf(pmax, __shfl_xor(pmax, 32));                                \
        float mnew  = fmaxf(m_run[g], pmax);                                     \
        float alpha = exp2f(m_run[g] - mnew);                                    \
        m_run[g] = mnew;                                                         \
        _Pragma("unroll")                                                        \
        for (int i = 0; i < 8; ++i) {                                            \
          _Pragma("unroll")                                                      \
          for (int r = 0; r < 4; ++r) acc[g][i][r] *= alpha;                     \
        }                                                                        \
        _Pragma("unroll")                                                        \
        for (int r = 0; r < 4; ++r) acc_l[g][r] *= alpha;                        \
      }                                                                          \
      _Pragma("unroll")                                                          \
      for (int b_ = 0; b_ < 4; ++b_) {                                           \
        _Pragma("unroll")                                                        \
        for (int r = 0; r < 4; ++r) {                                            \
          float p = exp2f(SC[g][b_][r] - m_run[g]);   /* bounded by 2^8 */       \
          pp[g][b_ >> 1][(b_ & 1)*4 + r] = (bf16_t)p;                            \
        }                                                                        \
      }                                                                          \
    }                                                                            \
    __builtin_amdgcn_s_setprio(1);                                               \
    _Pragma("unroll")                                                            \
    for (int ks = 0; ks < 2; ++ks) {                                             \
      acc_l[0] = __builtin_amdgcn_mfma_f32_16x16x32_bf16(onesf, pp[0][ks], acc_l[0], 0, 0, 0); \
      acc_l[1] = __builtin_amdgcn_mfma_f32_16x16x32_bf16(onesf, pp[1][ks], acc_l[1], 0, 0, 0); \
      _Pragma("unroll")                                                          \
      for (int db = 0; db < 8; ++db) {                                           \
        bf16x8 va = vf[ks*8 + db];                                               \
        acc[0][db] = __builtin_amdgcn_mfma_f32_16x16x32_bf16(va, pp[0][ks], acc[0][db], 0, 0, 0); \
        acc[1][db] = __builtin_amdgcn_mfma_f32_16x16x32_bf16(va, pp[1][ks], acc[1][db], 0, 0, 0); \
      }                                                                          \
    }                                                                            \
    __builtin_amdgcn_s_setprio(0);                                               \
  } while (0)

__global__ __launch_bounds__(256, 2) void attn_fwd(const float* __restrict__ Qg,
                                                   const bf16_t* __restrict__ Kp,
                                                   const bf16_t* __restrict__ Vp,
                                                   float* __restrict__ Og) {
  // chunked XCD swizzle: 512 blocks, XCD x owns logical [x*64, x*64+64) = 2 heads
  const int phys = blockIdx.x;
  const int logical = (phys & 7) * 64 + (phys >> 3);
  const int h  = logical >> 5;
  const int qt = logical & 31;       // q-tile of 128 rows
  const int tid  = threadIdx.x;
  const int wid  = tid >> 6;         // 0..3
  const int lane = tid & 63;
  const int l16  = lane & 15;
  const int lg   = lane >> 4;
  const int lo16 = lane * 16;

  __shared__ alignas(16) bf16_t Ks[2][8192];   // 16KB each, frag-major
  __shared__ alignas(16) bf16_t Vt[2][8192];   // 16KB each, frag-major

  // ---- Q fragments for 2 q-groups (B-operand of swapped QK^T) ----
  const float qs = 0.08838834764831845f * 1.4426950408889634f;
  bf16x8 qf[2][4];
  #pragma unroll
  for (int g = 0; g < 2; ++g) {
    const int qrow = qt*QB + wid*32 + g*16 + l16;
    const float* qp = Qg + (size_t)qrow*HD + h*DD + lg*8;
    #pragma unroll
    for (int c = 0; c < 4; ++c) {
      float4 a = *(const float4*)(qp + c*32);
      float4 b = *(const float4*)(qp + c*32 + 4);
      qf[g][c] = pack8(a, b, qs);
    }
  }
  bf16x8 onesf;
  #pragma unroll
  for (int j = 0; j < 8; ++j) onesf[j] = (bf16_t)1.0f;
  asm volatile("" ::: "memory");

  // ---- staging: pure linear global->LDS DMA (8x16B per thread per tile) ----
  const int lo = tid*16;
  auto issue = [&](int kt) {
    int b = kt & 1;
    const char* kg = (const char*)(Kp + (size_t)(h*NT + kt)*8192);
    const char* vg = (const char*)(Vp + (size_t)(h*NT + kt)*8192);
    char* kl = (char*)&Ks[b][0];
    char* vl = (char*)&Vt[b][0];
    #pragma unroll
    for (int p = 0; p < 4; ++p) gload_lds16(kg + lo + p*4096, kl + lo + p*4096);
    #pragma unroll
    for (int p = 0; p < 4; ++p) gload_lds16(vg + lo + p*4096, vl + lo + p*4096);
  };

  f32x4 acc[2][8];
  f32x4 acc_l[2];
  #pragma unroll
  for (int g = 0; g < 2; ++g) {
    #pragma unroll
    for (int i = 0; i < 8; ++i) acc[g][i] = (f32x4){0.f,0.f,0.f,0.f};
    acc_l[g] = (f32x4){0.f,0.f,0.f,0.f};
  }
  float m_run[2] = {-__builtin_inff(), -__builtin_inff()};

  issue(0);
  issue(1);
  asm volatile("s_waitcnt vmcnt(8)" ::: "memory");  // tile 0 arrived (8 of tile1 in flight)
  __builtin_amdgcn_s_barrier();
  __builtin_amdgcn_sched_barrier(0);

  // prologue QK(0)
  f32x4 sc[2][4];
  #pragma unroll
  for (int g = 0; g < 2; ++g)
    #pragma unroll
    for (int b = 0; b < 4; ++b) sc[g][b] = (f32x4){0.f,0.f,0.f,0.f};
  {
    const char* KsB = (const char*)&Ks[0][0] + lo16;
    QK_COMPUTE(sc, KsB);
  }

  for (int kt = 0; kt < NT-1; ++kt) {
    const int cur = kt & 1;
    // ---- V hoist (tile kt) from buf[cur] ----
    bf16x8 vf[16];
    {
      const char* VtB = (const char*)&Vt[cur][0] + lo16;
      #pragma unroll
      for (int f = 0; f < 16; ++f) vf[f] = *(const bf16x8*)(VtB + (f << 10));
    }
    // ---- SINGLE sync point per tile:
    //   lgkmcnt(0): my V-hoist reads of buf[cur] retired
    //   vmcnt(0):   my tile-(kt+1) DMA (issued last iter) landed
    //   barrier:    publishes both for ALL waves ->
    //               buf[cur] WAR-safe to overwrite; buf[cur^1] fully valid
    asm volatile("s_waitcnt vmcnt(0) lgkmcnt(0)" ::: "memory");
    __builtin_amdgcn_sched_barrier(0);
    __builtin_amdgcn_s_barrier();
    if (kt + 2 < NT) issue(kt + 2);          // DMA into buf[cur]
    __builtin_amdgcn_sched_barrier(0);

    // ---- QK(kt+1) -> sc_next  ||  softmax(kt) + PV(kt)  (independent DAGs) ----
    f32x4 scn[2][4];
    #pragma unroll
    for (int g = 0; g < 2; ++g)
      #pragma unroll
      for (int b = 0; b < 4; ++b) scn[g][b] = (f32x4){0.f,0.f,0.f,0.f};
    {
      const char* KsB = (const char*)&Ks[cur ^ 1][0] + lo16;
      QK_COMPUTE(scn, KsB);
    }
    SOFTMAX_PV(sc);

    #pragma unroll
    for (int g = 0; g < 2; ++g)
      #pragma unroll
      for (int b = 0; b < 4; ++b) sc[g][b] = scn[g][b];
  }

  // ---- tail tile NT-1: V hoist + softmax + PV (no more DMA) ----
  {
    bf16x8 vf[16];
    const char* VtB = (const char*)&Vt[(NT-1) & 1][0] + lo16;
    #pragma unroll
    for (int f = 0; f < 16; ++f) vf[f] = *(const bf16x8*)(VtB + (f << 10));
    SOFTMAX_PV(sc);
  }

  // ---- epilogue: normalize, store O (lane: q=g*16+l16, d=db*16+lg*4+r) ----
  #pragma unroll
  for (int g = 0; g < 2; ++g) {
    const int qrow = qt*QB + wid*32 + g*16 + l16;
    const float inv = 1.0f / acc_l[g][0];
    float* op = Og + (size_t)qrow*HD + h*DD + lg*4;
    #pragma unroll
    for (int db = 0; db < 8; ++db) {
      float4 o;
      o.x = acc[g][db][0]*inv; o.y = acc[g][db][1]*inv;
      o.z = acc[g][db][2]*inv; o.w = acc[g][db][3]*inv;
      *(float4*)(op + db*16) = o;
    }
  }
}

extern "C" void kernel_launch(void* const* d_in, const int* in_sizes, int n_in,
                              void* d_out, int out_size, void* d_ws, size_t ws_size,
                              hipStream_t stream) {
  const float* Q = (const float*)d_in[0];
  const float* K = (const float*)d_in[1];
  const float* V = (const float*)d_in[2];
  float* O = (float*)d_out;
  bf16_t* Kp = (bf16_t*)d_ws;                       // 16.78 MB
  bf16_t* Vp = Kp + (size_t)NH*S_LEN*DD;            // 16.78 MB
  prep_kv<<<dim3(NT, NH, 2), 256, 0, stream>>>(K, V, Kp, Vp);
  attn_fwd<<<dim3(512), 256, 0, stream>>>(Q, Kp, Vp, O);
}

// Round 22
// 168.918 us; speedup vs baseline: 1.1626x; 1.0450x over previous
//
#include <hip/hip_runtime.h>
#include <hip/hip_bf16.h>

#define S_LEN 4096
#define NH    16
#define DD    128
#define HD    2048
#define QB    128
#define KB    64
#define NT    (S_LEN/KB)

typedef __bf16 bf16_t;
typedef bf16_t bf16x8 __attribute__((ext_vector_type(8)));
typedef float  f32x4  __attribute__((ext_vector_type(4)));

static __device__ __forceinline__ bf16x8 pack8(float4 a, float4 b, float s) {
  bf16x8 v;
  v[0]=(bf16_t)(a.x*s); v[1]=(bf16_t)(a.y*s); v[2]=(bf16_t)(a.z*s); v[3]=(bf16_t)(a.w*s);
  v[4]=(bf16_t)(b.x*s); v[5]=(bf16_t)(b.y*s); v[6]=(bf16_t)(b.z*s); v[7]=(bf16_t)(b.w*s);
  return v;
}

static __device__ __forceinline__ void gload_lds16(const void* g, void* l) {
  __builtin_amdgcn_global_load_lds((const __attribute__((address_space(1))) void*)g,
                                   (__attribute__((address_space(3))) void*)l, 16, 0, 0);
}

// ---- fused prep: z=0 -> K frag-major tiles; z=1 -> V^T frag-major tiles ----
__global__ __launch_bounds__(256) void prep_kv(const float* __restrict__ Kg,
                                               const float* __restrict__ Vg,
                                               bf16_t* __restrict__ Kp,
                                               bf16_t* __restrict__ Vp) {
  const int kt = blockIdx.x, h = blockIdx.y, which = blockIdx.z, tid = threadIdx.x;
  const float* src = which ? Vg : Kg;
  __shared__ bf16_t tile[KB][DD + 8];
  #pragma unroll
  for (int it = 0; it < 8; ++it) {
    int lin4 = it*256 + tid;
    int r  = lin4 >> 5;
    int dc = (lin4 & 31) * 4;
    float4 a = *(const float4*)(src + (size_t)(kt*KB + r)*HD + h*DD + dc);
    tile[r][dc+0]=(bf16_t)a.x; tile[r][dc+1]=(bf16_t)a.y;
    tile[r][dc+2]=(bf16_t)a.z; tile[r][dc+3]=(bf16_t)a.w;
  }
  __syncthreads();
  if (which == 0) {
    bf16_t* out = Kp + (size_t)(h*NT + kt)*8192;
    #pragma unroll
    for (int it = 0; it < 4; ++it) {
      int cid = it*256 + tid;
      int f = cid >> 6, l = cid & 63;
      int b = f >> 2, c = f & 3;
      int row = b*16 + (l & 15);
      int d0  = c*32 + (l >> 4)*8;
      bf16x8 v = *(const bf16x8*)(&tile[row][d0]);
      *(bf16x8*)(out + (size_t)cid*8) = v;
    }
  } else {
    bf16_t* out = Vp + (size_t)(h*NT + kt)*8192;
    #pragma unroll
    for (int it = 0; it < 4; ++it) {
      int cid = it*256 + tid;
      int f = cid >> 6, l = cid & 63;
      int ks = f >> 3, db = f & 7;
      int d  = db*16 + (l & 15);
      int c0 = ks*32 + (l >> 4)*8;
      bf16x8 v;
      #pragma unroll
      for (int m = 0; m < 8; ++m) {
        int c = c0 + m;
        int k = 32*(c>>5) + 16*((c>>2)&1) + 4*((c>>3)&3) + (c&3);
        v[m] = tile[k][d];
      }
      *(bf16x8*)(out + (size_t)cid*8) = v;
    }
  }
}

// QK cluster: DST[2][4] = K-frags x qf (zero-init inside); reads base + lane*16 + imm
#define QK_COMPUTE(DST, KSBASE)                                                  \
  do {                                                                           \
    _Pragma("unroll")                                                            \
    for (int g_ = 0; g_ < 2; ++g_)                                               \
      _Pragma("unroll")                                                          \
      for (int b_ = 0; b_ < 4; ++b_) DST[g_][b_] = (f32x4){0.f,0.f,0.f,0.f};     \
    _Pragma("unroll")                                                            \
    for (int b_ = 0; b_ < 4; ++b_) {                                             \
      _Pragma("unroll")                                                          \
      for (int c_ = 0; c_ < 4; ++c_) {                                           \
        bf16x8 kb_ = *(const bf16x8*)((KSBASE) + ((b_*4 + c_) << 10));           \
        DST[0][b_] = __builtin_amdgcn_mfma_f32_16x16x32_bf16(kb_, qf[0][c_], DST[0][b_], 0, 0, 0); \
        DST[1][b_] = __builtin_amdgcn_mfma_f32_16x16x32_bf16(kb_, qf[1][c_], DST[1][b_], 0, 0, 0); \
      }                                                                          \
    }                                                                            \
  } while (0)

// softmax(SC) -> pp ; then PV from vf regs.
// LOCAL-pmax fast path: no cross-lane shuffles unless rescale needed.
#define SOFTMAX_PV(SC)                                                           \
  do {                                                                           \
    bf16x8 pp[2][2];                                                             \
    _Pragma("unroll")                                                            \
    for (int g = 0; g < 2; ++g) {                                                \
      float pmax;                                                                \
      {                                                                          \
        float a0 = fmaxf(fmaxf(SC[g][0][0], SC[g][0][1]), SC[g][0][2]);          \
        float a1 = fmaxf(fmaxf(SC[g][0][3], SC[g][1][0]), SC[g][1][1]);          \
        float a2 = fmaxf(fmaxf(SC[g][1][2], SC[g][1][3]), SC[g][2][0]);          \
        float a3 = fmaxf(fmaxf(SC[g][2][1], SC[g][2][2]), SC[g][2][3]);          \
        float a4 = fmaxf(fmaxf(SC[g][3][0], SC[g][3][1]), SC[g][3][2]);          \
        float b0 = fmaxf(fmaxf(a0, a1), a2);                                     \
        float b1 = fmaxf(fmaxf(a3, a4), SC[g][3][3]);                            \
        pmax = fmaxf(b0, b1);   /* LANE-LOCAL max (16 own scores) */             \
      }                                                                          \
      if (!__all(pmax - m_run[g] <= 8.0f)) {                                     \
        /* rare path: true row max via cross-lane, then rescale */               \
        pmax = fmaxf(pmax, __shfl_xor(pmax, 16));                                \
        pmax = fmaxf(pmax, __shfl_xor(pmax, 32));                                \
        float mnew  = fmaxf(m_run[g], pmax);                                     \
        float alpha = exp2f(m_run[g] - mnew);                                    \
        m_run[g] = mnew;                                                         \
        _Pragma("unroll")                                                        \
        for (int i = 0; i < 8; ++i) {                                            \
          _Pragma("unroll")                                                      \
          for (int r = 0; r < 4; ++r) acc[g][i][r] *= alpha;                     \
        }                                                                        \
        _Pragma("unroll")                                                        \
        for (int r = 0; r < 4; ++r) acc_l[g][r] *= alpha;                        \
      }                                                                          \
      _Pragma("unroll")                                                          \
      for (int b_ = 0; b_ < 4; ++b_) {                                           \
        _Pragma("unroll")                                                        \
        for (int r = 0; r < 4; ++r) {                                            \
          float p = exp2f(SC[g][b_][r] - m_run[g]);   /* bounded by 2^8 */       \
          pp[g][b_ >> 1][(b_ & 1)*4 + r] = (bf16_t)p;                            \
        }                                                                        \
      }                                                                          \
    }                                                                            \
    __builtin_amdgcn_s_setprio(1);                                               \
    _Pragma("unroll")                                                            \
    for (int ks = 0; ks < 2; ++ks) {                                             \
      acc_l[0] = __builtin_amdgcn_mfma_f32_16x16x32_bf16(onesf, pp[0][ks], acc_l[0], 0, 0, 0); \
      acc_l[1] = __builtin_amdgcn_mfma_f32_16x16x32_bf16(onesf, pp[1][ks], acc_l[1], 0, 0, 0); \
      _Pragma("unroll")                                                          \
      for (int db = 0; db < 8; ++db) {                                           \
        bf16x8 va = vf[ks*8 + db];                                               \
        acc[0][db] = __builtin_amdgcn_mfma_f32_16x16x32_bf16(va, pp[0][ks], acc[0][db], 0, 0, 0); \
        acc[1][db] = __builtin_amdgcn_mfma_f32_16x16x32_bf16(va, pp[1][ks], acc[1][db], 0, 0, 0); \
      }                                                                          \
    }                                                                            \
    __builtin_amdgcn_s_setprio(0);                                               \
  } while (0)

// one pipeline stage, CUR is a compile-time literal (buffer parity of KT):
//   V-hoist(KT) from buf[CUR] -> single sync -> issue(KT+2) -> QK(KT+1)->SNXT || SM+PV(KT) from SCUR
#define BODY(SCUR, SNXT, KT, CUR)                                                \
  do {                                                                           \
    bf16x8 vf[16];                                                               \
    {                                                                            \
      const char* VtB_ = (const char*)&Vt[CUR][0] + lo16;                        \
      _Pragma("unroll")                                                          \
      for (int f_ = 0; f_ < 16; ++f_) vf[f_] = *(const bf16x8*)(VtB_ + (f_ << 10)); \
    }                                                                            \
    asm volatile("s_waitcnt vmcnt(0) lgkmcnt(0)" ::: "memory");                  \
    __builtin_amdgcn_sched_barrier(0);                                           \
    __builtin_amdgcn_s_barrier();                                                \
    if ((KT) + 2 < NT) issue((KT) + 2, CUR);                                     \
    __builtin_amdgcn_sched_barrier(0);                                           \
    {                                                                            \
      const char* KsB_ = (const char*)&Ks[(CUR) ^ 1][0] + lo16;                  \
      QK_COMPUTE(SNXT, KsB_);                                                    \
    }                                                                            \
    SOFTMAX_PV(SCUR);                                                            \
  } while (0)

__global__ __launch_bounds__(256, 2) void attn_fwd(const float* __restrict__ Qg,
                                                   const bf16_t* __restrict__ Kp,
                                                   const bf16_t* __restrict__ Vp,
                                                   float* __restrict__ Og) {
  // chunked XCD swizzle: 512 blocks, XCD x owns logical [x*64, x*64+64) = 2 heads
  const int phys = blockIdx.x;
  const int logical = (phys & 7) * 64 + (phys >> 3);
  const int h  = logical >> 5;
  const int qt = logical & 31;       // q-tile of 128 rows
  const int tid  = threadIdx.x;
  const int wid  = tid >> 6;         // 0..3
  const int lane = tid & 63;
  const int l16  = lane & 15;
  const int lg   = lane >> 4;
  const int lo16 = lane * 16;

  __shared__ alignas(16) bf16_t Ks[2][8192];   // 16KB each, frag-major
  __shared__ alignas(16) bf16_t Vt[2][8192];   // 16KB each, frag-major

  // ---- Q fragments for 2 q-groups (B-operand of swapped QK^T) ----
  const float qs = 0.08838834764831845f * 1.4426950408889634f;
  bf16x8 qf[2][4];
  #pragma unroll
  for (int g = 0; g < 2; ++g) {
    const int qrow = qt*QB + wid*32 + g*16 + l16;
    const float* qp = Qg + (size_t)qrow*HD + h*DD + lg*8;
    #pragma unroll
    for (int c = 0; c < 4; ++c) {
      float4 a = *(const float4*)(qp + c*32);
      float4 b = *(const float4*)(qp + c*32 + 4);
      qf[g][c] = pack8(a, b, qs);
    }
  }
  bf16x8 onesf;
  #pragma unroll
  for (int j = 0; j < 8; ++j) onesf[j] = (bf16_t)1.0f;
  asm volatile("" ::: "memory");

  // ---- staging: pure linear global->LDS DMA (8x16B per thread per tile) ----
  const int lo = tid*16;
  auto issue = [&](int kt, int b) {
    const char* kg = (const char*)(Kp + (size_t)(h*NT + kt)*8192);
    const char* vg = (const char*)(Vp + (size_t)(h*NT + kt)*8192);
    char* kl = (char*)&Ks[b][0];
    char* vl = (char*)&Vt[b][0];
    #pragma unroll
    for (int p = 0; p < 4; ++p) gload_lds16(kg + lo + p*4096, kl + lo + p*4096);
    #pragma unroll
    for (int p = 0; p < 4; ++p) gload_lds16(vg + lo + p*4096, vl + lo + p*4096);
  };

  f32x4 acc[2][8];
  f32x4 acc_l[2];
  #pragma unroll
  for (int g = 0; g < 2; ++g) {
    #pragma unroll
    for (int i = 0; i < 8; ++i) acc[g][i] = (f32x4){0.f,0.f,0.f,0.f};
    acc_l[g] = (f32x4){0.f,0.f,0.f,0.f};
  }
  float m_run[2] = {-__builtin_inff(), -__builtin_inff()};

  issue(0, 0);
  issue(1, 1);
  asm volatile("s_waitcnt vmcnt(8)" ::: "memory");  // tile 0 arrived (8 of tile1 in flight)
  __builtin_amdgcn_s_barrier();
  __builtin_amdgcn_sched_barrier(0);

  // prologue QK(0) -> scA
  f32x4 scA[2][4], scB[2][4];
  {
    const char* KsB = (const char*)&Ks[0][0] + lo16;
    QK_COMPUTE(scA, KsB);
  }

  // NT-1 = 63 pipeline stages: 31 ping-pong pairs (kt=0..61) + 1 (kt=62), then tail
  for (int kt = 0; kt < NT-2; kt += 2) {
    BODY(scA, scB, kt,   0);
    BODY(scB, scA, kt+1, 1);
  }
  BODY(scA, scB, NT-2, 0);   // kt = 62: QK(63)->scB, SM+PV(62)

  // ---- tail tile NT-1 = 63: V hoist from buf[1] + softmax + PV (no more DMA) ----
  {
    bf16x8 vf[16];
    const char* VtB = (const char*)&Vt[1][0] + lo16;
    #pragma unroll
    for (int f = 0; f < 16; ++f) vf[f] = *(const bf16x8*)(VtB + (f << 10));
    SOFTMAX_PV(scB);
  }

  // ---- epilogue: normalize, store O (lane: q=g*16+l16, d=db*16+lg*4+r) ----
  #pragma unroll
  for (int g = 0; g < 2; ++g) {
    const int qrow = qt*QB + wid*32 + g*16 + l16;
    const float inv = 1.0f / acc_l[g][0];
    float* op = Og + (size_t)qrow*HD + h*DD + lg*4;
    #pragma unroll
    for (int db = 0; db < 8; ++db) {
      float4 o;
      o.x = acc[g][db][0]*inv; o.y = acc[g][db][1]*inv;
      o.z = acc[g][db][2]*inv; o.w = acc[g][db][3]*inv;
      *(float4*)(op + db*16) = o;
    }
  }
}

extern "C" void kernel_launch(void* const* d_in, const int* in_sizes, int n_in,
                              void* d_out, int out_size, void* d_ws, size_t ws_size,
                              hipStream_t stream) {
  const float* Q = (const float*)d_in[0];
  const float* K = (const float*)d_in[1];
  const float* V = (const float*)d_in[2];
  float* O = (float*)d_out;
  bf16_t* Kp = (bf16_t*)d_ws;                       // 16.78 MB
  bf16_t* Vp = Kp + (size_t)NH*S_LEN*DD;            // 16.78 MB
  prep_kv<<<dim3(NT, NH, 2), 256, 0, stream>>>(K, V, Kp, Vp);
  attn_fwd<<<dim3(512), 256, 0, stream>>>(Q, Kp, Vp, O);
}